// Round 11
// baseline (113.541 us; speedup 1.0000x reference)
//
#include <hip/hip_runtime.h>

namespace {

constexpr int T = 512;
constexpr int K = 4;
constexpr int G = 20000;
constexpr int EPG = 3;
constexpr int B = 512;
constexpr int BT = 8;                  // b's per slab -> 128B LDS rows
constexpr int NSLAB = B / BT;          // 64 (grid x, fast dim)
constexpr int NG = 8;                  // g-splits (grid y, slow dim)
constexpr int CH = 32;                 // g's per chunk (256 threads / 8 lanes)
constexpr int NCHUNK = 79;             // ceil(20000/8/32)
constexpr int GPB = NCHUNK * CH;       // 2528
constexpr int GPAD = NG * GPB;         // 20224
constexpr float SLOPE = 0.01f;

__device__ __forceinline__ float lrelu(float x) { return fmaxf(x, SLOPE * x); }
__device__ __forceinline__ float dot4(float4 a, float4 b) {
  return a.x * b.x + a.y * b.y + a.z * b.z + a.w * b.w;
}

// Prep: dense SoA records. R0/R1/R2 = w3 edge rows; RM = (bias, t0, t1, t2)
// (t's as raw ints). Padded g's: zero weights, t=0 (safe reads; store guarded).
__global__ __launch_bounds__(256) void prep_kernel(
    const float* __restrict__ w3, const float* __restrict__ b3,
    const int* __restrict__ edge, float4* __restrict__ R0,
    float4* __restrict__ R1, float4* __restrict__ R2, float4* __restrict__ RM) {
  const int g = blockIdx.x * 256 + threadIdx.x;  // 0..GPAD-1
  float4 a = make_float4(0.f, 0.f, 0.f, 0.f), b = a, c = a, m = a;
  if (g < G) {
    const float4* wp = reinterpret_cast<const float4*>(w3 + (size_t)g * (EPG * K));
    a = wp[0];
    b = wp[1];
    c = wp[2];
    m.x = b3[g];
    m.y = __int_as_float(edge[g * EPG + 0]);
    m.z = __int_as_float(edge[g * EPG + 1]);
    m.w = __int_as_float(edge[g * EPG + 2]);
  } else {
    m.y = m.z = m.w = __int_as_float(0);
  }
  R0[g] = a; R1[g] = b; R2[g] = c; RM[g] = m;
}

// Fused kernel, BT=8. LDS row t = 128B (8 b-chunks of 16B), chunk position
// swizzled by (b+t)&7:
//  - phase-1 ds_write_b128 (fixed b, lane=t): starts 4*((b+t)&7) spread over
//    all 8 bank-groups per 8-lane phase -> conflict-free writes.
//  - phase-2 gather: 8-lane cluster shares g (same t_e), lane b reads its
//    chunk -> cluster covers the full 128B row (each bank exactly once),
//    CONFLICT-FREE for arbitrary random t. This was the R7 bottleneck: 16B-
//    granular per-lane random addresses only hit 8 bank-group starts -> ~3x
//    phase conflicts -> ~3x DS time.
// Records dedup in the coalescer (8 lanes same addr); stores are 8 x 128B
// runs per wave; grid 64x8 = 512 blocks = exactly 2/CU, barrier-free g-loop.
__global__ __launch_bounds__(256, 2) void fused_kernel(
    const float* __restrict__ features, const float* __restrict__ w1,
    const float* __restrict__ b1, const float* __restrict__ w2,
    const float* __restrict__ b2, const float4* __restrict__ R0,
    const float4* __restrict__ R1, const float4* __restrict__ R2,
    const float4* __restrict__ RM, float* __restrict__ out) {
  __shared__ float lds[T * 32];  // 64 KB -> 2 blocks/CU
  const int tid = threadIdx.x;
  const int b0 = blockIdx.x * BT;
  const int gbase = blockIdx.y * GPB;

  // ---- Phase 1: h2 slab (8 b's) -> swizzled LDS rows ----
#pragma unroll
  for (int half = 0; half < 2; ++half) {
    const int t = half * 256 + tid;
    const float4 W1 = reinterpret_cast<const float4*>(w1)[t];
    const float4 B1 = reinterpret_cast<const float4*>(b1)[t];
    const float4 B2 = reinterpret_cast<const float4*>(b2)[t];
    const float4* W2 = reinterpret_cast<const float4*>(w2) + t * 4;
    const float4 r0 = W2[0];
    const float4 r1 = W2[1];
    const float4 r2 = W2[2];
    const float4 r3 = W2[3];
#pragma unroll
    for (int b = 0; b < BT; ++b) {
      const float f = features[(size_t)(b0 + b) * T + t];
      const float h0 = lrelu(f * W1.x + B1.x);
      const float h1 = lrelu(f * W1.y + B1.y);
      const float h2 = lrelu(f * W1.z + B1.z);
      const float h3 = lrelu(f * W1.w + B1.w);
      float4 o;
      o.x = lrelu(B2.x + h0 * r0.x + h1 * r1.x + h2 * r2.x + h3 * r3.x);
      o.y = lrelu(B2.y + h0 * r0.y + h1 * r1.y + h2 * r2.y + h3 * r3.y);
      o.z = lrelu(B2.z + h0 * r0.z + h1 * r1.z + h2 * r2.z + h3 * r3.z);
      o.w = lrelu(B2.w + h0 * r0.w + h1 * r1.w + h2 * r2.w + h3 * r3.w);
      const int sw = ((b + t) & 7) * 4;  // swizzled chunk position (dwords)
      *reinterpret_cast<float4*>(&lds[t * 32 + sw]) = o;
    }
  }
  __syncthreads();  // the only barrier

  const char* ldsc = reinterpret_cast<const char*>(lds);
  const int b = tid & 7;     // lane's b within the slab
  const int gsub = tid >> 3; // 0..31: cluster's g within the chunk

  // ---- Phase 2: barrier-free g-loop, 1-deep rec pipeline ----
  float4 pw0, pw1, pw2, pm;
  {
    const int g = gbase + gsub;
    pw0 = R0[g]; pw1 = R1[g]; pw2 = R2[g]; pm = RM[g];
  }
  for (int s = 0; s < NCHUNK; ++s) {
    const float4 c0 = pw0, c1 = pw1, c2 = pw2, cm = pm;
    const int g = gbase + s * CH + gsub;
    if (s + 1 < NCHUNK) {
      const int gn = gbase + (s + 1) * CH + gsub;
      pw0 = R0[gn]; pw1 = R1[gn]; pw2 = R2[gn]; pm = RM[gn];
    }
    const int t0 = __float_as_int(cm.y);
    const int t1 = __float_as_int(cm.z);
    const int t2 = __float_as_int(cm.w);
    const float4 v0 = *reinterpret_cast<const float4*>(
        ldsc + (t0 << 7) + (((b + t0) & 7) << 4));
    const float4 v1 = *reinterpret_cast<const float4*>(
        ldsc + (t1 << 7) + (((b + t1) & 7) << 4));
    const float4 v2 = *reinterpret_cast<const float4*>(
        ldsc + (t2 << 7) + (((b + t2) & 7) << 4));
    const float a = cm.x + dot4(v0, c0) + dot4(v1, c1) + dot4(v2, c2);
    if (g < G) out[(size_t)(b0 + b) * G + g] = a;
  }
}

}  // namespace

extern "C" void kernel_launch(void* const* d_in, const int* in_sizes, int n_in,
                              void* d_out, int out_size, void* d_ws, size_t ws_size,
                              hipStream_t stream) {
  const float* features = (const float*)d_in[0];
  const float* w1 = (const float*)d_in[1];
  const float* b1 = (const float*)d_in[2];
  const float* w2 = (const float*)d_in[3];
  const float* b2 = (const float*)d_in[4];
  const float* w3 = (const float*)d_in[5];
  const float* b3 = (const float*)d_in[6];
  const int* edge = (const int*)d_in[7];
  float* out = (float*)d_out;

  float4* R0 = (float4*)d_ws;  // 4 dense SoA arrays, 316 KB each
  float4* R1 = R0 + GPAD;
  float4* R2 = R1 + GPAD;
  float4* RM = R2 + GPAD;

  prep_kernel<<<GPAD / 256, 256, 0, stream>>>(w3, b3, edge, R0, R1, R2, RM);

  dim3 grid(NSLAB, NG);  // (64, 8): 512 blocks = exactly 2/CU
  fused_kernel<<<grid, 256, 0, stream>>>(features, w1, b1, w2, b2, R0, R1, R2,
                                         RM, out);
}

// Round 14
// 108.803 us; speedup vs baseline: 1.0436x; 1.0436x over previous
//
#include <hip/hip_runtime.h>

namespace {

constexpr int T = 512;
constexpr int K = 4;
constexpr int G = 20000;
constexpr int EPG = 3;
constexpr int B = 512;
constexpr int BT = 4;                  // b's per slab -> 64B LDS rows
constexpr int NSLAB = B / BT;          // 128 (grid x, fast dim)
constexpr int NG = 8;                  // g-splits (grid y, slow dim)
constexpr int CH = 64;                 // g's per chunk (256 threads / 4 lanes)
constexpr int GPB = 2560;              // g's per block
constexpr int NCHUNK = GPB / CH;       // 40
constexpr int GPAD = NG * GPB;         // 20480
constexpr int RS = 16;                 // row stride in dwords = 64 B exactly
constexpr float SLOPE = 0.01f;

__device__ __forceinline__ float lrelu(float x) { return fmaxf(x, SLOPE * x); }
__device__ __forceinline__ float dot4(float4 a, float4 b) {
  return a.x * b.x + a.y * b.y + a.z * b.z + a.w * b.w;
}

// Prep: dense SoA records. R0/R1/R2 = w3 edge rows; RM = (bias, t0, t1, t2)
// as raw ints. Padded g's: zero weights + t=0 (safe reads; stores guarded).
__global__ __launch_bounds__(256) void prep_kernel(
    const float* __restrict__ w3, const float* __restrict__ b3,
    const int* __restrict__ edge, float4* __restrict__ R0,
    float4* __restrict__ R1, float4* __restrict__ R2, float4* __restrict__ RM) {
  const int g = blockIdx.x * 256 + threadIdx.x;  // 0..GPAD-1
  float4 a = make_float4(0.f, 0.f, 0.f, 0.f), b = a, c = a, m = a;
  if (g < G) {
    const float4* wp = reinterpret_cast<const float4*>(w3 + (size_t)g * (EPG * K));
    a = wp[0];
    b = wp[1];
    c = wp[2];
    m.x = b3[g];
    m.y = __int_as_float(edge[g * EPG + 0]);
    m.z = __int_as_float(edge[g * EPG + 1]);
    m.w = __int_as_float(edge[g * EPG + 2]);
  } else {
    m.y = m.z = m.w = __int_as_float(0);
  }
  R0[g] = a; R1[g] = b; R2[g] = c; RM[g] = m;
}

// Fused kernel, BT=4, 64B rows + (b+t)&3 chunk swizzle:
//  - phase-1 writes: per 8-lane phase, even-t rows hit 4 distinct starts in
//    banks 0-15, odd-t rows in banks 16-31 -> conflict-free.
//  - gather: 4-lane cluster (same g) covers one full 64B row (16 banks once);
//    two clusters per phase collide only on same-parity t = 2-way = free.
//    => conflict-free gather at 32KB LDS (4 blocks/CU, 16 waves/CU) — fixes
//    R7's ~3x 16B-granular conflicts WITHOUT R11's occupancy cliff.
__global__ __launch_bounds__(256, 4) void fused_kernel(
    const float* __restrict__ features, const float* __restrict__ w1,
    const float* __restrict__ b1, const float* __restrict__ w2,
    const float* __restrict__ b2, const float4* __restrict__ R0,
    const float4* __restrict__ R1, const float4* __restrict__ R2,
    const float4* __restrict__ RM, float* __restrict__ out) {
  __shared__ float lds[T * RS];  // 32 KB
  const int tid = threadIdx.x;
  const int b0 = blockIdx.x * BT;
  const int gbase = blockIdx.y * GPB;

  // ---- Phase 1: h2 slab (4 b's) -> swizzled 64B LDS rows ----
#pragma unroll
  for (int half = 0; half < 2; ++half) {
    const int t = half * 256 + tid;
    const float4 W1 = reinterpret_cast<const float4*>(w1)[t];
    const float4 B1 = reinterpret_cast<const float4*>(b1)[t];
    const float4 B2 = reinterpret_cast<const float4*>(b2)[t];
    const float4* W2 = reinterpret_cast<const float4*>(w2) + t * 4;
    const float4 r0 = W2[0];
    const float4 r1 = W2[1];
    const float4 r2 = W2[2];
    const float4 r3 = W2[3];
#pragma unroll
    for (int b = 0; b < BT; ++b) {
      const float f = features[(size_t)(b0 + b) * T + t];
      const float h0 = lrelu(f * W1.x + B1.x);
      const float h1 = lrelu(f * W1.y + B1.y);
      const float h2 = lrelu(f * W1.z + B1.z);
      const float h3 = lrelu(f * W1.w + B1.w);
      float4 o;
      o.x = lrelu(B2.x + h0 * r0.x + h1 * r1.x + h2 * r2.x + h3 * r3.x);
      o.y = lrelu(B2.y + h0 * r0.y + h1 * r1.y + h2 * r2.y + h3 * r3.y);
      o.z = lrelu(B2.z + h0 * r0.z + h1 * r1.z + h2 * r2.z + h3 * r3.z);
      o.w = lrelu(B2.w + h0 * r0.w + h1 * r1.w + h2 * r2.w + h3 * r3.w);
      const int sw = ((b + t) & 3) * 4;  // swizzled chunk (dwords)
      *reinterpret_cast<float4*>(&lds[t * RS + sw]) = o;
    }
  }
  __syncthreads();  // the only barrier

  const char* ldsc = reinterpret_cast<const char*>(lds);
  const int b = tid & 3;      // lane's b within the slab
  const int gsub = tid >> 2;  // 0..63: cluster's g within the chunk

  // ---- Phase 2: barrier-free g-loop, 1-deep rec pipeline ----
  float4 pw0, pw1, pw2, pm;
  {
    const int g = gbase + gsub;
    pw0 = R0[g]; pw1 = R1[g]; pw2 = R2[g]; pm = RM[g];
  }
  for (int s = 0; s < NCHUNK; ++s) {
    const float4 c0 = pw0, c1 = pw1, c2 = pw2, cm = pm;
    const int g = gbase + s * CH + gsub;
    if (s + 1 < NCHUNK) {
      const int gn = gbase + (s + 1) * CH + gsub;
      pw0 = R0[gn]; pw1 = R1[gn]; pw2 = R2[gn]; pm = RM[gn];
    }
    const int t0 = __float_as_int(cm.y);
    const int t1 = __float_as_int(cm.z);
    const int t2 = __float_as_int(cm.w);
    const float4 v0 = *reinterpret_cast<const float4*>(
        ldsc + (t0 << 6) + (((b + t0) & 3) << 4));
    const float4 v1 = *reinterpret_cast<const float4*>(
        ldsc + (t1 << 6) + (((b + t1) & 3) << 4));
    const float4 v2 = *reinterpret_cast<const float4*>(
        ldsc + (t2 << 6) + (((b + t2) & 3) << 4));
    const float a = cm.x + dot4(v0, c0) + dot4(v1, c1) + dot4(v2, c2);
    if (g < G) out[(size_t)(b0 + b) * G + g] = a;
  }
}

}  // namespace

extern "C" void kernel_launch(void* const* d_in, const int* in_sizes, int n_in,
                              void* d_out, int out_size, void* d_ws, size_t ws_size,
                              hipStream_t stream) {
  const float* features = (const float*)d_in[0];
  const float* w1 = (const float*)d_in[1];
  const float* b1 = (const float*)d_in[2];
  const float* w2 = (const float*)d_in[3];
  const float* b2 = (const float*)d_in[4];
  const float* w3 = (const float*)d_in[5];
  const float* b3 = (const float*)d_in[6];
  const int* edge = (const int*)d_in[7];
  float* out = (float*)d_out;

  float4* R0 = (float4*)d_ws;  // 4 dense SoA arrays, 320 KB each
  float4* R1 = R0 + GPAD;
  float4* R2 = R1 + GPAD;
  float4* RM = R2 + GPAD;

  prep_kernel<<<GPAD / 256, 256, 0, stream>>>(w3, b3, edge, R0, R1, R2, RM);

  dim3 grid(NSLAB, NG);  // (128, 8) = 1024 blocks = 4 blocks/CU, 16 waves/CU
  fused_kernel<<<grid, 256, 0, stream>>>(features, w1, b1, w2, b2, R0, R1, R2,
                                         RM, out);
}